// Round 1
// baseline (2533.839 us; speedup 1.0000x reference)
//
#include <hip/hip_runtime.h>
#include <hip/hip_bf16.h>
#include <math.h>

// Problem constants
#define NROWS 100000
#define DDIM  512
#define KCL   32
#define H1DIM 512
#define H2DIM 256
#define LN2PI_2 0.9189385332046727f
#define NCHUNK 196   // ceil(100000/512)

__device__ __forceinline__ float softplus_f(float v) {
    return v > 20.f ? v : log1pf(expf(v));
}

// ---------------------------------------------------------------------------
// GEMM + bias + softplus:  C[M,Nc] = softplus(A[M,Kd] @ B[Kd,Nc] + bias[Nc])
// 64x64x16 tile, 256 threads, 4x4 per-thread microtile.
// ---------------------------------------------------------------------------
__global__ __launch_bounds__(256) void gemm_bias_softplus(
    const float* __restrict__ A, const float* __restrict__ B,
    const float* __restrict__ bias, float* __restrict__ C,
    int M, int Nc, int Kd)
{
    const int BM = 64, BN = 64, BK = 16;
    __shared__ float As[BK][BM + 4];   // stride 68 floats -> 16B-aligned rows
    __shared__ float Bs[BK][BN + 4];

    int tid = threadIdx.x;
    int row0 = blockIdx.y * BM;
    int col0 = blockIdx.x * BN;
    int tx = tid & 15, ty = tid >> 4;

    int arow = tid >> 2;          // 0..63
    int acol = (tid & 3) << 2;    // 0,4,8,12
    int brow = tid >> 4;          // 0..15
    int bcol = (tid & 15) << 2;   // 0..60

    float acc[4][4] = {};

    for (int k0 = 0; k0 < Kd; k0 += BK) {
        float4 a4 = make_float4(0.f, 0.f, 0.f, 0.f);
        if (row0 + arow < M)
            a4 = *(const float4*)&A[(size_t)(row0 + arow) * Kd + k0 + acol];
        float4 b4 = *(const float4*)&B[(size_t)(k0 + brow) * Nc + col0 + bcol];
        __syncthreads();
        As[acol + 0][arow] = a4.x;
        As[acol + 1][arow] = a4.y;
        As[acol + 2][arow] = a4.z;
        As[acol + 3][arow] = a4.w;
        *(float4*)&Bs[brow][bcol] = b4;
        __syncthreads();
        #pragma unroll
        for (int kk = 0; kk < BK; kk++) {
            float4 av = *(const float4*)&As[kk][ty * 4];
            float4 bv = *(const float4*)&Bs[kk][tx * 4];
            acc[0][0] += av.x * bv.x; acc[0][1] += av.x * bv.y;
            acc[0][2] += av.x * bv.z; acc[0][3] += av.x * bv.w;
            acc[1][0] += av.y * bv.x; acc[1][1] += av.y * bv.y;
            acc[1][2] += av.y * bv.z; acc[1][3] += av.y * bv.w;
            acc[2][0] += av.z * bv.x; acc[2][1] += av.z * bv.y;
            acc[2][2] += av.z * bv.z; acc[2][3] += av.z * bv.w;
            acc[3][0] += av.w * bv.x; acc[3][1] += av.w * bv.y;
            acc[3][2] += av.w * bv.z; acc[3][3] += av.w * bv.w;
        }
    }

    int colb = col0 + tx * 4;
    float4 bb = *(const float4*)&bias[colb];
    #pragma unroll
    for (int i = 0; i < 4; i++) {
        int r = row0 + ty * 4 + i;
        if (r < M) {
            float4 o;
            o.x = softplus_f(acc[i][0] + bb.x);
            o.y = softplus_f(acc[i][1] + bb.y);
            o.z = softplus_f(acc[i][2] + bb.z);
            o.w = softplus_f(acc[i][3] + bb.w);
            *(float4*)&C[(size_t)r * Nc + colb] = o;
        }
    }
}

// ---------------------------------------------------------------------------
// logits = h2 @ W3 + b3, softmax over K=32 -> att [N,K]
// one thread = one row; W3 resident in LDS; h2 staged in 32-col tiles.
// ---------------------------------------------------------------------------
__global__ __launch_bounds__(256) void logits_softmax(
    const float* __restrict__ h2, const float* __restrict__ W3,
    const float* __restrict__ b3, float* __restrict__ att)
{
    __shared__ float W3s[H2DIM][KCL];   // 32 KB
    __shared__ float Hs[256][33];       // 33.8 KB (pad to kill 64-way conflicts)
    __shared__ float b3s[KCL];

    int tid = threadIdx.x;
    int n0 = blockIdx.x * 256;
    int n = n0 + tid;

    for (int idx = tid; idx < H2DIM * KCL; idx += 256)
        ((float*)W3s)[idx] = W3[idx];
    if (tid < KCL) b3s[tid] = b3[tid];

    float acc[KCL] = {};

    for (int t = 0; t < H2DIM / 32; t++) {
        __syncthreads();
        for (int idx = tid; idx < 256 * 32; idx += 256) {
            int r = idx >> 5, c = idx & 31;
            int g = n0 + r;
            Hs[r][c] = (g < NROWS) ? h2[(size_t)g * H2DIM + t * 32 + c] : 0.f;
        }
        __syncthreads();
        #pragma unroll 8
        for (int j = 0; j < 32; j++) {
            float hv = Hs[tid][j];
            #pragma unroll
            for (int k4 = 0; k4 < KCL / 4; k4++) {
                float4 w = *(const float4*)&W3s[t * 32 + j][k4 * 4];
                acc[k4 * 4 + 0] += hv * w.x;
                acc[k4 * 4 + 1] += hv * w.y;
                acc[k4 * 4 + 2] += hv * w.z;
                acc[k4 * 4 + 3] += hv * w.w;
            }
        }
    }

    if (n < NROWS) {
        float m = -INFINITY;
        #pragma unroll
        for (int k = 0; k < KCL; k++) { acc[k] += b3s[k]; m = fmaxf(m, acc[k]); }
        float s = 0.f;
        #pragma unroll
        for (int k = 0; k < KCL; k++) { acc[k] = expf(acc[k] - m); s += acc[k]; }
        float inv = 1.f / s;
        #pragma unroll
        for (int k4 = 0; k4 < KCL / 4; k4++) {
            float4 o;
            o.x = acc[k4 * 4 + 0] * inv;
            o.y = acc[k4 * 4 + 1] * inv;
            o.z = acc[k4 * 4 + 2] * inv;
            o.w = acc[k4 * 4 + 3] * inv;
            *(float4*)&att[(size_t)n * KCL + k4 * 4] = o;
        }
    }
}

// ---------------------------------------------------------------------------
// Partial weighted moments: per (row-chunk c, d-tile t) block computes
// S1_p[k][dd] = sum_r att[r,k]*x[r,d], S2_p = sum att*x^2, plus att col sums.
// No atomics: partials to P, reduced by stats_reduce.
// ---------------------------------------------------------------------------
__global__ __launch_bounds__(256) void stats_partial(
    const float* __restrict__ x, const float* __restrict__ att,
    float* __restrict__ P, float* __restrict__ Patt)
{
    __shared__ float as_[128][32];
    __shared__ float xs[128][32];

    int tid = threadIdx.x;
    int c = blockIdx.x;     // row chunk (512 rows)
    int t = blockIdx.y;     // d tile (32 cols)
    int k = tid & 31;
    int dg = tid >> 5;      // 0..7, covers d = dg*4 .. dg*4+3

    float s1[4] = {}, s2[4] = {};
    float asum = 0.f;
    int r0 = c * 512;

    for (int sub = 0; sub < 4; sub++) {
        int rr0 = r0 + sub * 128;
        __syncthreads();
        for (int idx = tid; idx < 128 * 32; idx += 256) {
            int r = idx >> 5, cc = idx & 31;
            int g = rr0 + r;
            as_[r][cc] = (g < NROWS) ? att[(size_t)g * KCL + cc] : 0.f;
            xs[r][cc]  = (g < NROWS) ? x[(size_t)g * DDIM + t * 32 + cc] : 0.f;
        }
        __syncthreads();
        for (int r = 0; r < 128; r++) {
            float a = as_[r][k];
            if (dg == 0) asum += a;
            float4 xv = *(const float4*)&xs[r][dg * 4];
            float ax;
            ax = a * xv.x; s1[0] += ax; s2[0] += ax * xv.x;
            ax = a * xv.y; s1[1] += ax; s2[1] += ax * xv.y;
            ax = a * xv.z; s1[2] += ax; s2[2] += ax * xv.z;
            ax = a * xv.w; s1[3] += ax; s2[3] += ax * xv.w;
        }
    }

    size_t base = ((size_t)(t * NCHUNK + c)) * 2048;
    #pragma unroll
    for (int i = 0; i < 4; i++) {
        P[base + k * 32 + dg * 4 + i]        = s1[i];
        P[base + 1024 + k * 32 + dg * 4 + i] = s2[i];
    }
    if (t == 0 && dg == 0) Patt[c * 32 + k] = asum;
}

// ---------------------------------------------------------------------------
// Reduce partials over chunks -> S12 ([S1 | S2], each [K][D]) and att_sum[K]
// ---------------------------------------------------------------------------
__global__ __launch_bounds__(256) void stats_reduce(
    const float* __restrict__ P, const float* __restrict__ Patt,
    float* __restrict__ S12, float* __restrict__ att_sum)
{
    int t = blockIdx.x;
    int tid = threadIdx.x;
    for (int e = tid; e < 2048; e += 256) {
        float s = 0.f;
        for (int c = 0; c < NCHUNK; c++)
            s += P[((size_t)(t * NCHUNK + c)) * 2048 + e];
        int which = e >> 10;
        int ee = e & 1023;
        int k = ee >> 5, dd = ee & 31;
        S12[(size_t)which * KCL * DDIM + k * DDIM + t * 32 + dd] = s;
    }
    if (t == 0 && tid < KCL) {
        float s = 0.f;
        for (int c = 0; c < NCHUNK; c++) s += Patt[c * 32 + tid];
        att_sum[tid] = s;
    }
}

// ---------------------------------------------------------------------------
// Finalize stats: means/vars, write vars to out, and produce
// nivT[d][k] = -0.5/var, mivT[d][k] = mean/var,
// konst[k] = -0.5*sum(m^2/v) - 0.5*sum(log v) - D*ln(2pi)/2
// ---------------------------------------------------------------------------
__global__ __launch_bounds__(256) void finalize_stats(
    const float* __restrict__ S12, const float* __restrict__ att_sum,
    float* __restrict__ nivT, float* __restrict__ mivT,
    float* __restrict__ konst, float* __restrict__ vars_out)
{
    int k = blockIdx.x;
    int tid = threadIdx.x;
    __shared__ float red[256];

    float inv_as = 1.f / att_sum[k];
    float csum = 0.f, lsum = 0.f;
    for (int d = tid; d < DDIM; d += 256) {
        float mean = S12[k * DDIM + d] * inv_as;
        float ex2  = S12[KCL * DDIM + k * DDIM + d] * inv_as;
        float var  = ex2 - mean * mean;
        vars_out[k * DDIM + d] = var;
        float iv = 1.f / var;
        nivT[d * KCL + k] = -0.5f * iv;
        mivT[d * KCL + k] = mean * iv;
        csum += mean * mean * iv;
        lsum += logf(var);
    }
    red[tid] = csum;
    __syncthreads();
    for (int s = 128; s > 0; s >>= 1) {
        if (tid < s) red[tid] += red[tid + s];
        __syncthreads();
    }
    float ctot = red[0];
    __syncthreads();
    red[tid] = lsum;
    __syncthreads();
    for (int s = 128; s > 0; s >>= 1) {
        if (tid < s) red[tid] += red[tid + s];
        __syncthreads();
    }
    if (tid == 0)
        konst[k] = -0.5f * ctot - 0.5f * red[0] - DDIM * LN2PI_2;
}

// ---------------------------------------------------------------------------
// gmm_log[n,k] = sum_d ( x^2 * niv[d][k] + x * miv[d][k] ) + konst[k]
// one thread = one row; niv/miv tiles broadcast from LDS as float4.
// ---------------------------------------------------------------------------
__global__ __launch_bounds__(256) void gmm_out(
    const float* __restrict__ x, const float* __restrict__ nivT,
    const float* __restrict__ mivT, const float* __restrict__ konst,
    float* __restrict__ out)
{
    __shared__ float Xs[256][33];
    __shared__ float NIVs[32][32];
    __shared__ float MIVs[32][32];
    __shared__ float ks[KCL];

    int tid = threadIdx.x;
    int n0 = blockIdx.x * 256;
    int n = n0 + tid;
    if (tid < KCL) ks[tid] = konst[tid];

    float acc[KCL] = {};

    for (int t = 0; t < DDIM / 32; t++) {
        __syncthreads();
        for (int idx = tid; idx < 256 * 32; idx += 256) {
            int r = idx >> 5, c = idx & 31;
            int g = n0 + r;
            Xs[r][c] = (g < NROWS) ? x[(size_t)g * DDIM + t * 32 + c] : 0.f;
        }
        for (int idx = tid; idx < 1024; idx += 256) {
            ((float*)NIVs)[idx] = nivT[t * 1024 + idx];
            ((float*)MIVs)[idx] = mivT[t * 1024 + idx];
        }
        __syncthreads();
        #pragma unroll 4
        for (int dd = 0; dd < 32; dd++) {
            float xv = Xs[tid][dd];
            float x2 = xv * xv;
            #pragma unroll
            for (int k4 = 0; k4 < KCL / 4; k4++) {
                float4 nv = *(const float4*)&NIVs[dd][k4 * 4];
                float4 mv = *(const float4*)&MIVs[dd][k4 * 4];
                acc[k4 * 4 + 0] += x2 * nv.x + xv * mv.x;
                acc[k4 * 4 + 1] += x2 * nv.y + xv * mv.y;
                acc[k4 * 4 + 2] += x2 * nv.z + xv * mv.z;
                acc[k4 * 4 + 3] += x2 * nv.w + xv * mv.w;
            }
        }
    }

    if (n < NROWS) {
        #pragma unroll
        for (int k4 = 0; k4 < KCL / 4; k4++) {
            float4 o;
            o.x = acc[k4 * 4 + 0] + ks[k4 * 4 + 0];
            o.y = acc[k4 * 4 + 1] + ks[k4 * 4 + 1];
            o.z = acc[k4 * 4 + 2] + ks[k4 * 4 + 2];
            o.w = acc[k4 * 4 + 3] + ks[k4 * 4 + 3];
            *(float4*)&out[(size_t)n * KCL + k4 * 4] = o;
        }
    }
}

// ---------------------------------------------------------------------------
extern "C" void kernel_launch(void* const* d_in, const int* in_sizes, int n_in,
                              void* d_out, int out_size, void* d_ws, size_t ws_size,
                              hipStream_t stream)
{
    const float* x  = (const float*)d_in[0];
    const float* W1 = (const float*)d_in[1];
    const float* b1 = (const float*)d_in[2];
    const float* W2 = (const float*)d_in[3];
    const float* b2 = (const float*)d_in[4];
    const float* W3 = (const float*)d_in[5];
    const float* b3 = (const float*)d_in[6];
    float* out = (float*)d_out;              // [N*K] gmm_log, then [K*D] vars

    float* ws = (float*)d_ws;
    float* h1      = ws;                         // 51,200,000
    float* h2      = h1 + (size_t)NROWS * H1DIM; // 25,600,000
    float* att     = h2 + (size_t)NROWS * H2DIM; // 3,200,000
    float* P       = att + (size_t)NROWS * KCL;  // 16*196*2048 = 6,422,528
    float* Patt    = P + (size_t)16 * NCHUNK * 2048;  // 6272
    float* S12     = Patt + NCHUNK * KCL;        // 32768
    float* att_sum = S12 + 2 * KCL * DDIM;       // 32
    float* nivT    = att_sum + KCL;              // 16384
    float* mivT    = nivT + KCL * DDIM;          // 16384
    float* konst   = mivT + KCL * DDIM;          // 32
    (void)ws_size; (void)in_sizes; (void)n_in; (void)out_size;

    int mblocks = (NROWS + 63) / 64;     // 1563

    // h1 = softplus(x @ W1 + b1)
    gemm_bias_softplus<<<dim3(H1DIM / 64, mblocks), 256, 0, stream>>>(
        x, W1, b1, h1, NROWS, H1DIM, DDIM);
    // h2 = softplus(h1 @ W2 + b2)
    gemm_bias_softplus<<<dim3(H2DIM / 64, mblocks), 256, 0, stream>>>(
        h1, W2, b2, h2, NROWS, H2DIM, H1DIM);
    // att = softmax(h2 @ W3 + b3)
    logits_softmax<<<dim3((NROWS + 255) / 256), 256, 0, stream>>>(h2, W3, b3, att);
    // partial weighted moments
    stats_partial<<<dim3(NCHUNK, DDIM / 32), 256, 0, stream>>>(x, att, P, Patt);
    // reduce partials
    stats_reduce<<<dim3(DDIM / 32), 256, 0, stream>>>(P, Patt, S12, att_sum);
    // finalize: vars (to out), niv/miv/konst
    finalize_stats<<<dim3(KCL), 256, 0, stream>>>(
        S12, att_sum, nivT, mivT, konst, out + (size_t)NROWS * KCL);
    // gmm_log
    gmm_out<<<dim3((NROWS + 255) / 256), 256, 0, stream>>>(x, nivT, mivT, konst, out);
}

// Round 2
// 1646.407 us; speedup vs baseline: 1.5390x; 1.5390x over previous
//
#include <hip/hip_runtime.h>
#include <hip/hip_bf16.h>
#include <math.h>

// Problem constants
#define NROWS 100000
#define DDIM  512
#define KCL   32
#define H1DIM 512
#define H2DIM 256
#define LN2PI_2 0.9189385332046727f
#define NCHUNK 196   // ceil(100000/512)

typedef __attribute__((ext_vector_type(8))) short short8;
typedef __attribute__((ext_vector_type(4))) float floatx4;

__device__ __forceinline__ float softplus_f(float v) {
    return v > 20.f ? v : log1pf(expf(v));
}

__device__ __forceinline__ unsigned short f2bf_rne(float f) {
    unsigned int u = __float_as_uint(f);
    return (unsigned short)((u + 0x7fffu + ((u >> 16) & 1u)) >> 16);
}
__device__ __forceinline__ float bf2f(unsigned short h) {
    return __uint_as_float(((unsigned int)h) << 16);
}

// ---------------------------------------------------------------------------
// Split W[k][n] (fp32) into transposed bf16 hi/lo: BhT/BlT are [N][K].
// ---------------------------------------------------------------------------
__global__ __launch_bounds__(256) void split_weightT(
    const float* __restrict__ W, int Kd, int Nc,
    short* __restrict__ BhT, short* __restrict__ BlT)
{
    int idx = blockIdx.x * 256 + threadIdx.x;
    if (idx >= Kd * Nc) return;
    int n = idx % Nc, k = idx / Nc;
    float w = W[idx];
    unsigned short hi = f2bf_rne(w);
    unsigned short lo = f2bf_rne(w - bf2f(hi));
    BhT[(size_t)n * Kd + k] = (short)hi;
    BlT[(size_t)n * Kd + k] = (short)lo;
}

// ---------------------------------------------------------------------------
// C = softplus(A @ B + bias) via split-bf16 MFMA (3 mfma per k-step ~ fp32).
// A fp32 [M][Kd]; BhT/BlT bf16 [Nc][Kd]. Tile 128x128x32, 256 thr (4 waves),
// each wave 64x64 via 4x4 frags of v_mfma_f32_16x16x32_bf16.
// ---------------------------------------------------------------------------
#define LDA 40   // LDS row stride in bf16 elements (80 B): pads bank strides
__global__ __launch_bounds__(256) void gemm_split_softplus(
    const float* __restrict__ A, const short* __restrict__ BhT,
    const short* __restrict__ BlT, const float* __restrict__ bias,
    float* __restrict__ C, int M, int Nc, int Kd)
{
    __shared__ short As_hi[128 * LDA];
    __shared__ short As_lo[128 * LDA];
    __shared__ short Bs_hi[128 * LDA];
    __shared__ short Bs_lo[128 * LDA];

    const int tid = threadIdx.x;
    const int lane = tid & 63;
    const int lm = lane & 15;
    const int lq = lane >> 4;
    const int wid = tid >> 6;
    const int wrow = (wid & 1) * 64;
    const int wcol = (wid >> 1) * 64;

    const int row0 = blockIdx.y * 128;
    const int col0 = blockIdx.x * 128;

    floatx4 acc[4][4];
    #pragma unroll
    for (int i = 0; i < 4; i++)
        #pragma unroll
        for (int j = 0; j < 4; j++)
            acc[i][j] = (floatx4){0.f, 0.f, 0.f, 0.f};

    const int nk = Kd >> 5;
    for (int kt = 0; kt < nk; kt++) {
        __syncthreads();
        // ---- stage A (fp32 -> split bf16), 128 rows x 32 k ----
        #pragma unroll
        for (int h = 0; h < 2; h++) {
            int u = tid + h * 256;
            int r = u >> 2;
            int kb = (u & 3) << 3;
            int gr = row0 + r;
            float fv[8] = {0.f, 0.f, 0.f, 0.f, 0.f, 0.f, 0.f, 0.f};
            if (gr < M) {
                const float* ap = &A[(size_t)gr * Kd + (kt << 5) + kb];
                float4 f0 = *(const float4*)ap;
                float4 f1 = *(const float4*)(ap + 4);
                fv[0] = f0.x; fv[1] = f0.y; fv[2] = f0.z; fv[3] = f0.w;
                fv[4] = f1.x; fv[5] = f1.y; fv[6] = f1.z; fv[7] = f1.w;
            }
            short8 vh, vl;
            #pragma unroll
            for (int e = 0; e < 8; e++) {
                unsigned short hb = f2bf_rne(fv[e]);
                vh[e] = (short)hb;
                vl[e] = (short)f2bf_rne(fv[e] - bf2f(hb));
            }
            *(short8*)&As_hi[r * LDA + kb] = vh;
            *(short8*)&As_lo[r * LDA + kb] = vl;
        }
        // ---- stage B (pre-split bf16, [N][K] so k is contiguous) ----
        #pragma unroll
        for (int h = 0; h < 2; h++) {
            int u = tid + h * 256;
            int n = u >> 2;
            int kb = (u & 3) << 3;
            const size_t go = (size_t)(col0 + n) * Kd + (kt << 5) + kb;
            *(short8*)&Bs_hi[n * LDA + kb] = *(const short8*)&BhT[go];
            *(short8*)&Bs_lo[n * LDA + kb] = *(const short8*)&BlT[go];
        }
        __syncthreads();

        // ---- fragment loads ----
        short8 ah[4], al[4], bh[4], bl[4];
        #pragma unroll
        for (int i = 0; i < 4; i++) {
            int off = (wrow + i * 16 + lm) * LDA + lq * 8;
            ah[i] = *(const short8*)&As_hi[off];
            al[i] = *(const short8*)&As_lo[off];
        }
        #pragma unroll
        for (int j = 0; j < 4; j++) {
            int off = (wcol + j * 16 + lm) * LDA + lq * 8;
            bh[j] = *(const short8*)&Bs_hi[off];
            bl[j] = *(const short8*)&Bs_lo[off];
        }
        // ---- 48 MFMA: hi*hi + hi*lo + lo*hi ----
        #pragma unroll
        for (int i = 0; i < 4; i++)
            #pragma unroll
            for (int j = 0; j < 4; j++) {
                acc[i][j] = __builtin_amdgcn_mfma_f32_16x16x32_bf16(
                    ah[i], bh[j], acc[i][j], 0, 0, 0);
                acc[i][j] = __builtin_amdgcn_mfma_f32_16x16x32_bf16(
                    ah[i], bl[j], acc[i][j], 0, 0, 0);
                acc[i][j] = __builtin_amdgcn_mfma_f32_16x16x32_bf16(
                    al[i], bh[j], acc[i][j], 0, 0, 0);
            }
    }

    // ---- epilogue: bias + softplus, C/D layout col=lane&15 row=lq*4+reg ----
    float bb[4];
    #pragma unroll
    for (int j = 0; j < 4; j++)
        bb[j] = bias[col0 + wcol + j * 16 + lm];

    #pragma unroll
    for (int i = 0; i < 4; i++) {
        #pragma unroll
        for (int reg = 0; reg < 4; reg++) {
            int r = row0 + wrow + i * 16 + lq * 4 + reg;
            if (r < M) {
                #pragma unroll
                for (int j = 0; j < 4; j++) {
                    int c = col0 + wcol + j * 16 + lm;
                    C[(size_t)r * Nc + c] = softplus_f(acc[i][j][reg] + bb[j]);
                }
            }
        }
    }
}

// ---------------------------------------------------------------------------
// logits = h2 @ W3 + b3, softmax over K=32 -> att [N,K]
// ---------------------------------------------------------------------------
__global__ __launch_bounds__(256) void logits_softmax(
    const float* __restrict__ h2, const float* __restrict__ W3,
    const float* __restrict__ b3, float* __restrict__ att)
{
    __shared__ float W3s[H2DIM][KCL];
    __shared__ float Hs[256][33];
    __shared__ float b3s[KCL];

    int tid = threadIdx.x;
    int n0 = blockIdx.x * 256;
    int n = n0 + tid;

    for (int idx = tid; idx < H2DIM * KCL; idx += 256)
        ((float*)W3s)[idx] = W3[idx];
    if (tid < KCL) b3s[tid] = b3[tid];

    float acc[KCL] = {};

    for (int t = 0; t < H2DIM / 32; t++) {
        __syncthreads();
        for (int idx = tid; idx < 256 * 32; idx += 256) {
            int r = idx >> 5, c = idx & 31;
            int g = n0 + r;
            Hs[r][c] = (g < NROWS) ? h2[(size_t)g * H2DIM + t * 32 + c] : 0.f;
        }
        __syncthreads();
        #pragma unroll 8
        for (int j = 0; j < 32; j++) {
            float hv = Hs[tid][j];
            #pragma unroll
            for (int k4 = 0; k4 < KCL / 4; k4++) {
                float4 w = *(const float4*)&W3s[t * 32 + j][k4 * 4];
                acc[k4 * 4 + 0] += hv * w.x;
                acc[k4 * 4 + 1] += hv * w.y;
                acc[k4 * 4 + 2] += hv * w.z;
                acc[k4 * 4 + 3] += hv * w.w;
            }
        }
    }

    if (n < NROWS) {
        float m = -INFINITY;
        #pragma unroll
        for (int k = 0; k < KCL; k++) { acc[k] += b3s[k]; m = fmaxf(m, acc[k]); }
        float s = 0.f;
        #pragma unroll
        for (int k = 0; k < KCL; k++) { acc[k] = expf(acc[k] - m); s += acc[k]; }
        float inv = 1.f / s;
        #pragma unroll
        for (int k4 = 0; k4 < KCL / 4; k4++) {
            float4 o;
            o.x = acc[k4 * 4 + 0] * inv;
            o.y = acc[k4 * 4 + 1] * inv;
            o.z = acc[k4 * 4 + 2] * inv;
            o.w = acc[k4 * 4 + 3] * inv;
            *(float4*)&att[(size_t)n * KCL + k4 * 4] = o;
        }
    }
}

// ---------------------------------------------------------------------------
// Partial weighted moments (no atomics; reduced by stats_reduce).
// ---------------------------------------------------------------------------
__global__ __launch_bounds__(256) void stats_partial(
    const float* __restrict__ x, const float* __restrict__ att,
    float* __restrict__ P, float* __restrict__ Patt)
{
    __shared__ float as_[128][32];
    __shared__ float xs[128][32];

    int tid = threadIdx.x;
    int c = blockIdx.x;
    int t = blockIdx.y;
    int k = tid & 31;
    int dg = tid >> 5;

    float s1[4] = {}, s2[4] = {};
    float asum = 0.f;
    int r0 = c * 512;

    for (int sub = 0; sub < 4; sub++) {
        int rr0 = r0 + sub * 128;
        __syncthreads();
        for (int idx = tid; idx < 128 * 32; idx += 256) {
            int r = idx >> 5, cc = idx & 31;
            int g = rr0 + r;
            as_[r][cc] = (g < NROWS) ? att[(size_t)g * KCL + cc] : 0.f;
            xs[r][cc]  = (g < NROWS) ? x[(size_t)g * DDIM + t * 32 + cc] : 0.f;
        }
        __syncthreads();
        for (int r = 0; r < 128; r++) {
            float a = as_[r][k];
            if (dg == 0) asum += a;
            float4 xv = *(const float4*)&xs[r][dg * 4];
            float ax;
            ax = a * xv.x; s1[0] += ax; s2[0] += ax * xv.x;
            ax = a * xv.y; s1[1] += ax; s2[1] += ax * xv.y;
            ax = a * xv.z; s1[2] += ax; s2[2] += ax * xv.z;
            ax = a * xv.w; s1[3] += ax; s2[3] += ax * xv.w;
        }
    }

    size_t base = ((size_t)(t * NCHUNK + c)) * 2048;
    #pragma unroll
    for (int i = 0; i < 4; i++) {
        P[base + k * 32 + dg * 4 + i]        = s1[i];
        P[base + 1024 + k * 32 + dg * 4 + i] = s2[i];
    }
    if (t == 0 && dg == 0) Patt[c * 32 + k] = asum;
}

__global__ __launch_bounds__(256) void stats_reduce(
    const float* __restrict__ P, const float* __restrict__ Patt,
    float* __restrict__ S12, float* __restrict__ att_sum)
{
    int t = blockIdx.x;
    int tid = threadIdx.x;
    for (int e = tid; e < 2048; e += 256) {
        float s = 0.f;
        for (int c = 0; c < NCHUNK; c++)
            s += P[((size_t)(t * NCHUNK + c)) * 2048 + e];
        int which = e >> 10;
        int ee = e & 1023;
        int k = ee >> 5, dd = ee & 31;
        S12[(size_t)which * KCL * DDIM + k * DDIM + t * 32 + dd] = s;
    }
    if (t == 0 && tid < KCL) {
        float s = 0.f;
        for (int c = 0; c < NCHUNK; c++) s += Patt[c * 32 + tid];
        att_sum[tid] = s;
    }
}

__global__ __launch_bounds__(256) void finalize_stats(
    const float* __restrict__ S12, const float* __restrict__ att_sum,
    float* __restrict__ nivT, float* __restrict__ mivT,
    float* __restrict__ konst, float* __restrict__ vars_out)
{
    int k = blockIdx.x;
    int tid = threadIdx.x;
    __shared__ float red[256];

    float inv_as = 1.f / att_sum[k];
    float csum = 0.f, lsum = 0.f;
    for (int d = tid; d < DDIM; d += 256) {
        float mean = S12[k * DDIM + d] * inv_as;
        float ex2  = S12[KCL * DDIM + k * DDIM + d] * inv_as;
        float var  = ex2 - mean * mean;
        vars_out[k * DDIM + d] = var;
        float iv = 1.f / var;
        nivT[d * KCL + k] = -0.5f * iv;
        mivT[d * KCL + k] = mean * iv;
        csum += mean * mean * iv;
        lsum += logf(var);
    }
    red[tid] = csum;
    __syncthreads();
    for (int s = 128; s > 0; s >>= 1) {
        if (tid < s) red[tid] += red[tid + s];
        __syncthreads();
    }
    float ctot = red[0];
    __syncthreads();
    red[tid] = lsum;
    __syncthreads();
    for (int s = 128; s > 0; s >>= 1) {
        if (tid < s) red[tid] += red[tid + s];
        __syncthreads();
    }
    if (tid == 0)
        konst[k] = -0.5f * ctot - 0.5f * red[0] - DDIM * LN2PI_2;
}

__global__ __launch_bounds__(256) void gmm_out(
    const float* __restrict__ x, const float* __restrict__ nivT,
    const float* __restrict__ mivT, const float* __restrict__ konst,
    float* __restrict__ out)
{
    __shared__ float Xs[256][33];
    __shared__ float NIVs[32][32];
    __shared__ float MIVs[32][32];
    __shared__ float ks[KCL];

    int tid = threadIdx.x;
    int n0 = blockIdx.x * 256;
    int n = n0 + tid;
    if (tid < KCL) ks[tid] = konst[tid];

    float acc[KCL] = {};

    for (int t = 0; t < DDIM / 32; t++) {
        __syncthreads();
        for (int idx = tid; idx < 256 * 32; idx += 256) {
            int r = idx >> 5, c = idx & 31;
            int g = n0 + r;
            Xs[r][c] = (g < NROWS) ? x[(size_t)g * DDIM + t * 32 + c] : 0.f;
        }
        for (int idx = tid; idx < 1024; idx += 256) {
            ((float*)NIVs)[idx] = nivT[t * 1024 + idx];
            ((float*)MIVs)[idx] = mivT[t * 1024 + idx];
        }
        __syncthreads();
        #pragma unroll 4
        for (int dd = 0; dd < 32; dd++) {
            float xv = Xs[tid][dd];
            float x2 = xv * xv;
            #pragma unroll
            for (int k4 = 0; k4 < KCL / 4; k4++) {
                float4 nv = *(const float4*)&NIVs[dd][k4 * 4];
                float4 mv = *(const float4*)&MIVs[dd][k4 * 4];
                acc[k4 * 4 + 0] += x2 * nv.x + xv * mv.x;
                acc[k4 * 4 + 1] += x2 * nv.y + xv * mv.y;
                acc[k4 * 4 + 2] += x2 * nv.z + xv * mv.z;
                acc[k4 * 4 + 3] += x2 * nv.w + xv * mv.w;
            }
        }
    }

    if (n < NROWS) {
        #pragma unroll
        for (int k4 = 0; k4 < KCL / 4; k4++) {
            float4 o;
            o.x = acc[k4 * 4 + 0] + ks[k4 * 4 + 0];
            o.y = acc[k4 * 4 + 1] + ks[k4 * 4 + 1];
            o.z = acc[k4 * 4 + 2] + ks[k4 * 4 + 2];
            o.w = acc[k4 * 4 + 3] + ks[k4 * 4 + 3];
            *(float4*)&out[(size_t)n * KCL + k4 * 4] = o;
        }
    }
}

// ---------------------------------------------------------------------------
extern "C" void kernel_launch(void* const* d_in, const int* in_sizes, int n_in,
                              void* d_out, int out_size, void* d_ws, size_t ws_size,
                              hipStream_t stream)
{
    const float* x  = (const float*)d_in[0];
    const float* W1 = (const float*)d_in[1];
    const float* b1 = (const float*)d_in[2];
    const float* W2 = (const float*)d_in[3];
    const float* b2 = (const float*)d_in[4];
    const float* W3 = (const float*)d_in[5];
    const float* b3 = (const float*)d_in[6];
    float* out = (float*)d_out;              // [N*K] gmm_log, then [K*D] vars

    float* ws = (float*)d_ws;
    float* h1      = ws;                         // 51,200,000
    float* h2      = h1 + (size_t)NROWS * H1DIM; // 25,600,000
    float* att     = h2 + (size_t)NROWS * H2DIM; // 3,200,000
    float* P       = att + (size_t)NROWS * KCL;  // 16*196*2048 = 6,422,528
    float* Patt    = P + (size_t)16 * NCHUNK * 2048;
    float* S12     = Patt + NCHUNK * KCL;
    float* att_sum = S12 + 2 * KCL * DDIM;
    float* nivT    = att_sum + KCL;
    float* mivT    = nivT + KCL * DDIM;
    float* konst   = mivT + KCL * DDIM;
    (void)ws_size; (void)in_sizes; (void)n_in; (void)out_size;

    // Weight splits overlay the P region: only alive before stats_partial
    // writes P (stream-ordered, graph-safe). 786432 shorts << P's 25.7 MB.
    short* W1hT = (short*)P;                 // [512][512]
    short* W1lT = W1hT + H1DIM * DDIM;
    short* W2hT = W1lT + H1DIM * DDIM;       // [256][512]
    short* W2lT = W2hT + H2DIM * H1DIM;

    split_weightT<<<dim3((DDIM * H1DIM + 255) / 256), 256, 0, stream>>>(
        W1, DDIM, H1DIM, W1hT, W1lT);
    split_weightT<<<dim3((H1DIM * H2DIM + 255) / 256), 256, 0, stream>>>(
        W2, H1DIM, H2DIM, W2hT, W2lT);

    int mblocks = (NROWS + 127) / 128;   // 782

    // h1 = softplus(x @ W1 + b1)  [split-bf16 MFMA]
    gemm_split_softplus<<<dim3(H1DIM / 128, mblocks), 256, 0, stream>>>(
        x, W1hT, W1lT, b1, h1, NROWS, H1DIM, DDIM);
    // h2 = softplus(h1 @ W2 + b2) [split-bf16 MFMA]
    gemm_split_softplus<<<dim3(H2DIM / 128, mblocks), 256, 0, stream>>>(
        h1, W2hT, W2lT, b2, h2, NROWS, H2DIM, H1DIM);
    // att = softmax(h2 @ W3 + b3)
    logits_softmax<<<dim3((NROWS + 255) / 256), 256, 0, stream>>>(h2, W3, b3, att);
    // partial weighted moments
    stats_partial<<<dim3(NCHUNK, DDIM / 32), 256, 0, stream>>>(x, att, P, Patt);
    // reduce partials
    stats_reduce<<<dim3(DDIM / 32), 256, 0, stream>>>(P, Patt, S12, att_sum);
    // finalize: vars (to out), niv/miv/konst
    finalize_stats<<<dim3(KCL), 256, 0, stream>>>(
        S12, att_sum, nivT, mivT, konst, out + (size_t)NROWS * KCL);
    // gmm_log
    gmm_out<<<dim3((NROWS + 255) / 256), 256, 0, stream>>>(x, nivT, mivT, konst, out);
}

// Round 3
// 1279.709 us; speedup vs baseline: 1.9800x; 1.2865x over previous
//
#include <hip/hip_runtime.h>
#include <hip/hip_bf16.h>
#include <math.h>

// Problem constants
#define NROWS 100000
#define DDIM  512
#define KCL   32
#define H1DIM 512
#define H2DIM 256
#define LN2PI_2 0.9189385332046727f
#define NCHUNK 196   // ceil(100000/512)

typedef __attribute__((ext_vector_type(8))) short short8;
typedef __attribute__((ext_vector_type(4))) short shortx4;
typedef __attribute__((ext_vector_type(4))) float floatx4;

__device__ __forceinline__ float softplus_f(float v) {
    return v > 20.f ? v : log1pf(expf(v));
}

__device__ __forceinline__ unsigned short f2bf_rne(float f) {
    unsigned int u = __float_as_uint(f);
    return (unsigned short)((u + 0x7fffu + ((u >> 16) & 1u)) >> 16);
}
__device__ __forceinline__ float bf2f(unsigned short h) {
    return __uint_as_float(((unsigned int)h) << 16);
}

// ---------------------------------------------------------------------------
// Split W[k][n] (fp32) into transposed bf16 hi/lo: BhT/BlT are [N][K].
// ---------------------------------------------------------------------------
__global__ __launch_bounds__(256) void split_weightT(
    const float* __restrict__ W, int Kd, int Nc,
    short* __restrict__ BhT, short* __restrict__ BlT)
{
    int idx = blockIdx.x * 256 + threadIdx.x;
    if (idx >= Kd * Nc) return;
    int n = idx % Nc, k = idx / Nc;
    float w = W[idx];
    unsigned short hi = f2bf_rne(w);
    unsigned short lo = f2bf_rne(w - bf2f(hi));
    BhT[(size_t)n * Kd + k] = (short)hi;
    BlT[(size_t)n * Kd + k] = (short)lo;
}

// ---------------------------------------------------------------------------
// C = softplus(A @ B + bias) via split-bf16 MFMA (3 mfma per k-step ~ fp32).
// ---------------------------------------------------------------------------
#define LDA 40   // LDS row stride in bf16 elements (80 B)
__global__ __launch_bounds__(256) void gemm_split_softplus(
    const float* __restrict__ A, const short* __restrict__ BhT,
    const short* __restrict__ BlT, const float* __restrict__ bias,
    float* __restrict__ C, int M, int Nc, int Kd)
{
    __shared__ short As_hi[128 * LDA];
    __shared__ short As_lo[128 * LDA];
    __shared__ short Bs_hi[128 * LDA];
    __shared__ short Bs_lo[128 * LDA];

    const int tid = threadIdx.x;
    const int lane = tid & 63;
    const int lm = lane & 15;
    const int lq = lane >> 4;
    const int wid = tid >> 6;
    const int wrow = (wid & 1) * 64;
    const int wcol = (wid >> 1) * 64;

    const int row0 = blockIdx.y * 128;
    const int col0 = blockIdx.x * 128;

    floatx4 acc[4][4];
    #pragma unroll
    for (int i = 0; i < 4; i++)
        #pragma unroll
        for (int j = 0; j < 4; j++)
            acc[i][j] = (floatx4){0.f, 0.f, 0.f, 0.f};

    const int nk = Kd >> 5;
    for (int kt = 0; kt < nk; kt++) {
        __syncthreads();
        #pragma unroll
        for (int h = 0; h < 2; h++) {
            int u = tid + h * 256;
            int r = u >> 2;
            int kb = (u & 3) << 3;
            int gr = row0 + r;
            float fv[8] = {0.f, 0.f, 0.f, 0.f, 0.f, 0.f, 0.f, 0.f};
            if (gr < M) {
                const float* ap = &A[(size_t)gr * Kd + (kt << 5) + kb];
                float4 f0 = *(const float4*)ap;
                float4 f1 = *(const float4*)(ap + 4);
                fv[0] = f0.x; fv[1] = f0.y; fv[2] = f0.z; fv[3] = f0.w;
                fv[4] = f1.x; fv[5] = f1.y; fv[6] = f1.z; fv[7] = f1.w;
            }
            short8 vh, vl;
            #pragma unroll
            for (int e = 0; e < 8; e++) {
                unsigned short hb = f2bf_rne(fv[e]);
                vh[e] = (short)hb;
                vl[e] = (short)f2bf_rne(fv[e] - bf2f(hb));
            }
            *(short8*)&As_hi[r * LDA + kb] = vh;
            *(short8*)&As_lo[r * LDA + kb] = vl;
        }
        #pragma unroll
        for (int h = 0; h < 2; h++) {
            int u = tid + h * 256;
            int n = u >> 2;
            int kb = (u & 3) << 3;
            const size_t go = (size_t)(col0 + n) * Kd + (kt << 5) + kb;
            *(short8*)&Bs_hi[n * LDA + kb] = *(const short8*)&BhT[go];
            *(short8*)&Bs_lo[n * LDA + kb] = *(const short8*)&BlT[go];
        }
        __syncthreads();

        short8 ah[4], al[4], bh[4], bl[4];
        #pragma unroll
        for (int i = 0; i < 4; i++) {
            int off = (wrow + i * 16 + lm) * LDA + lq * 8;
            ah[i] = *(const short8*)&As_hi[off];
            al[i] = *(const short8*)&As_lo[off];
        }
        #pragma unroll
        for (int j = 0; j < 4; j++) {
            int off = (wcol + j * 16 + lm) * LDA + lq * 8;
            bh[j] = *(const short8*)&Bs_hi[off];
            bl[j] = *(const short8*)&Bs_lo[off];
        }
        #pragma unroll
        for (int i = 0; i < 4; i++)
            #pragma unroll
            for (int j = 0; j < 4; j++) {
                acc[i][j] = __builtin_amdgcn_mfma_f32_16x16x32_bf16(
                    ah[i], bh[j], acc[i][j], 0, 0, 0);
                acc[i][j] = __builtin_amdgcn_mfma_f32_16x16x32_bf16(
                    ah[i], bl[j], acc[i][j], 0, 0, 0);
                acc[i][j] = __builtin_amdgcn_mfma_f32_16x16x32_bf16(
                    al[i], bh[j], acc[i][j], 0, 0, 0);
            }
    }

    float bb[4];
    #pragma unroll
    for (int j = 0; j < 4; j++)
        bb[j] = bias[col0 + wcol + j * 16 + lm];

    #pragma unroll
    for (int i = 0; i < 4; i++) {
        #pragma unroll
        for (int reg = 0; reg < 4; reg++) {
            int r = row0 + wrow + i * 16 + lq * 4 + reg;
            if (r < M) {
                #pragma unroll
                for (int j = 0; j < 4; j++) {
                    int c = col0 + wcol + j * 16 + lm;
                    C[(size_t)r * Nc + c] = softplus_f(acc[i][j][reg] + bb[j]);
                }
            }
        }
    }
}

// ---------------------------------------------------------------------------
// logits = h2 @ W3 + b3, softmax over K=32 -> att [N,K]
// ---------------------------------------------------------------------------
__global__ __launch_bounds__(256) void logits_softmax(
    const float* __restrict__ h2, const float* __restrict__ W3,
    const float* __restrict__ b3, float* __restrict__ att)
{
    __shared__ float W3s[H2DIM][KCL];
    __shared__ float Hs[256][33];
    __shared__ float b3s[KCL];

    int tid = threadIdx.x;
    int n0 = blockIdx.x * 256;
    int n = n0 + tid;

    for (int idx = tid; idx < H2DIM * KCL; idx += 256)
        ((float*)W3s)[idx] = W3[idx];
    if (tid < KCL) b3s[tid] = b3[tid];

    float acc[KCL] = {};

    for (int t = 0; t < H2DIM / 32; t++) {
        __syncthreads();
        for (int idx = tid; idx < 256 * 32; idx += 256) {
            int r = idx >> 5, c = idx & 31;
            int g = n0 + r;
            Hs[r][c] = (g < NROWS) ? h2[(size_t)g * H2DIM + t * 32 + c] : 0.f;
        }
        __syncthreads();
        #pragma unroll 8
        for (int j = 0; j < 32; j++) {
            float hv = Hs[tid][j];
            #pragma unroll
            for (int k4 = 0; k4 < KCL / 4; k4++) {
                float4 w = *(const float4*)&W3s[t * 32 + j][k4 * 4];
                acc[k4 * 4 + 0] += hv * w.x;
                acc[k4 * 4 + 1] += hv * w.y;
                acc[k4 * 4 + 2] += hv * w.z;
                acc[k4 * 4 + 3] += hv * w.w;
            }
        }
    }

    if (n < NROWS) {
        float m = -INFINITY;
        #pragma unroll
        for (int k = 0; k < KCL; k++) { acc[k] += b3s[k]; m = fmaxf(m, acc[k]); }
        float s = 0.f;
        #pragma unroll
        for (int k = 0; k < KCL; k++) { acc[k] = expf(acc[k] - m); s += acc[k]; }
        float inv = 1.f / s;
        #pragma unroll
        for (int k4 = 0; k4 < KCL / 4; k4++) {
            float4 o;
            o.x = acc[k4 * 4 + 0] * inv;
            o.y = acc[k4 * 4 + 1] * inv;
            o.z = acc[k4 * 4 + 2] * inv;
            o.w = acc[k4 * 4 + 3] * inv;
            *(float4*)&att[(size_t)n * KCL + k4 * 4] = o;
        }
    }
}

// ---------------------------------------------------------------------------
// Partial weighted moments (no atomics; reduced by stats_reduce).
// ---------------------------------------------------------------------------
__global__ __launch_bounds__(256) void stats_partial(
    const float* __restrict__ x, const float* __restrict__ att,
    float* __restrict__ P, float* __restrict__ Patt)
{
    __shared__ float as_[128][32];
    __shared__ float xs[128][32];

    int tid = threadIdx.x;
    int c = blockIdx.x;
    int t = blockIdx.y;
    int k = tid & 31;
    int dg = tid >> 5;

    float s1[4] = {}, s2[4] = {};
    float asum = 0.f;
    int r0 = c * 512;

    for (int sub = 0; sub < 4; sub++) {
        int rr0 = r0 + sub * 128;
        __syncthreads();
        for (int idx = tid; idx < 128 * 32; idx += 256) {
            int r = idx >> 5, cc = idx & 31;
            int g = rr0 + r;
            as_[r][cc] = (g < NROWS) ? att[(size_t)g * KCL + cc] : 0.f;
            xs[r][cc]  = (g < NROWS) ? x[(size_t)g * DDIM + t * 32 + cc] : 0.f;
        }
        __syncthreads();
        for (int r = 0; r < 128; r++) {
            float a = as_[r][k];
            if (dg == 0) asum += a;
            float4 xv = *(const float4*)&xs[r][dg * 4];
            float ax;
            ax = a * xv.x; s1[0] += ax; s2[0] += ax * xv.x;
            ax = a * xv.y; s1[1] += ax; s2[1] += ax * xv.y;
            ax = a * xv.z; s1[2] += ax; s2[2] += ax * xv.z;
            ax = a * xv.w; s1[3] += ax; s2[3] += ax * xv.w;
        }
    }

    size_t base = ((size_t)(t * NCHUNK + c)) * 2048;
    #pragma unroll
    for (int i = 0; i < 4; i++) {
        P[base + k * 32 + dg * 4 + i]        = s1[i];
        P[base + 1024 + k * 32 + dg * 4 + i] = s2[i];
    }
    if (t == 0 && dg == 0) Patt[c * 32 + k] = asum;
}

// ---------------------------------------------------------------------------
// Reduce partials: 128 blocks (16 d-tiles x 8 e-slices), 1 element/thread.
// ---------------------------------------------------------------------------
__global__ __launch_bounds__(256) void stats_reduce(
    const float* __restrict__ P, const float* __restrict__ Patt,
    float* __restrict__ S12, float* __restrict__ att_sum)
{
    int t = blockIdx.x >> 3;
    int s = blockIdx.x & 7;
    int e = s * 256 + threadIdx.x;
    float sum = 0.f;
    for (int c = 0; c < NCHUNK; c++)
        sum += P[((size_t)(t * NCHUNK + c)) * 2048 + e];
    int which = e >> 10;
    int ee = e & 1023;
    int k = ee >> 5, dd = ee & 31;
    S12[(size_t)which * KCL * DDIM + k * DDIM + t * 32 + dd] = sum;

    if (blockIdx.x == 0 && threadIdx.x < KCL) {
        float as = 0.f;
        for (int c = 0; c < NCHUNK; c++) as += Patt[c * 32 + threadIdx.x];
        att_sum[threadIdx.x] = as;
    }
}

// ---------------------------------------------------------------------------
// Finalize stats: vars (to out), bf16 B' = [-0.5/v | m/v] per class, konst.
// ---------------------------------------------------------------------------
__global__ __launch_bounds__(256) void finalize_stats(
    const float* __restrict__ S12, const float* __restrict__ att_sum,
    short* __restrict__ Bp, float* __restrict__ konst,
    float* __restrict__ vars_out)
{
    int k = blockIdx.x;
    int tid = threadIdx.x;
    __shared__ float red[256];

    float inv_as = 1.f / att_sum[k];
    float csum = 0.f, lsum = 0.f;
    for (int d = tid; d < DDIM; d += 256) {
        float mean = S12[k * DDIM + d] * inv_as;
        float ex2  = S12[KCL * DDIM + k * DDIM + d] * inv_as;
        float var  = ex2 - mean * mean;
        vars_out[k * DDIM + d] = var;
        float iv = 1.f / var;
        Bp[(size_t)k * 1024 + d]       = (short)f2bf_rne(-0.5f * iv);
        Bp[(size_t)k * 1024 + 512 + d] = (short)f2bf_rne(mean * iv);
        csum += mean * mean * iv;
        lsum += logf(var);
    }
    red[tid] = csum;
    __syncthreads();
    for (int s = 128; s > 0; s >>= 1) {
        if (tid < s) red[tid] += red[tid + s];
        __syncthreads();
    }
    float ctot = red[0];
    __syncthreads();
    red[tid] = lsum;
    __syncthreads();
    for (int s = 128; s > 0; s >>= 1) {
        if (tid < s) red[tid] += red[tid + s];
        __syncthreads();
    }
    if (tid == 0)
        konst[k] = -0.5f * ctot - 0.5f * red[0] - DDIM * LN2PI_2;
}

// ---------------------------------------------------------------------------
// gmm_log via MFMA: out[n,k] = [x^2|x] @ Bp[k]^T + konst[k].
// Block: 256 thr (4 waves), 256 rows x 32 cols. x read ONCE: per 32-d tile,
// stage bf16(x^2) and bf16(x) tiles, 2 accumulation passes against Bp.
// ---------------------------------------------------------------------------
#define LDG 40
__global__ __launch_bounds__(256) void gmm_out_mfma(
    const float* __restrict__ x, const short* __restrict__ Bp,
    const float* __restrict__ konst, float* __restrict__ out)
{
    __shared__ short As_sq[256 * LDG];
    __shared__ short As_x[256 * LDG];

    const int tid = threadIdx.x;
    const int lane = tid & 63;
    const int lm = lane & 15;
    const int lq = lane >> 4;
    const int wid = tid >> 6;
    const int row0 = blockIdx.x * 256;

    floatx4 acc[4][2];
    #pragma unroll
    for (int i = 0; i < 4; i++)
        #pragma unroll
        for (int j = 0; j < 2; j++)
            acc[i][j] = (floatx4){0.f, 0.f, 0.f, 0.f};

    for (int dt = 0; dt < 16; dt++) {
        __syncthreads();
        // stage 256 rows x 32 d: fp32 -> bf16(x^2), bf16(x)
        #pragma unroll
        for (int h = 0; h < 8; h++) {
            int u = tid + h * 256;        // 0..2047
            int r = u >> 3;               // 0..255
            int seg = (u & 7) << 2;       // 0,4,..,28
            int gr = row0 + r;
            float4 v = make_float4(0.f, 0.f, 0.f, 0.f);
            if (gr < NROWS)
                v = *(const float4*)&x[(size_t)gr * DDIM + dt * 32 + seg];
            shortx4 sx, sq;
            sx[0] = (short)f2bf_rne(v.x); sq[0] = (short)f2bf_rne(v.x * v.x);
            sx[1] = (short)f2bf_rne(v.y); sq[1] = (short)f2bf_rne(v.y * v.y);
            sx[2] = (short)f2bf_rne(v.z); sq[2] = (short)f2bf_rne(v.z * v.z);
            sx[3] = (short)f2bf_rne(v.w); sq[3] = (short)f2bf_rne(v.w * v.w);
            *(shortx4*)&As_x[r * LDG + seg]  = sx;
            *(shortx4*)&As_sq[r * LDG + seg] = sq;
        }
        __syncthreads();

        short8 a_sq[4], a_x[4], b_sq[2], b_x[2];
        #pragma unroll
        for (int i = 0; i < 4; i++) {
            int off = (wid * 64 + i * 16 + lm) * LDG + lq * 8;
            a_sq[i] = *(const short8*)&As_sq[off];
            a_x[i]  = *(const short8*)&As_x[off];
        }
        #pragma unroll
        for (int j = 0; j < 2; j++) {
            const size_t bo = (size_t)(j * 16 + lm) * 1024 + dt * 32 + lq * 8;
            b_sq[j] = *(const short8*)&Bp[bo];
            b_x[j]  = *(const short8*)&Bp[bo + 512];
        }
        #pragma unroll
        for (int i = 0; i < 4; i++)
            #pragma unroll
            for (int j = 0; j < 2; j++) {
                acc[i][j] = __builtin_amdgcn_mfma_f32_16x16x32_bf16(
                    a_sq[i], b_sq[j], acc[i][j], 0, 0, 0);
                acc[i][j] = __builtin_amdgcn_mfma_f32_16x16x32_bf16(
                    a_x[i], b_x[j], acc[i][j], 0, 0, 0);
            }
    }

    float kst[2];
    kst[0] = konst[lm];
    kst[1] = konst[16 + lm];

    #pragma unroll
    for (int i = 0; i < 4; i++) {
        #pragma unroll
        for (int reg = 0; reg < 4; reg++) {
            int r = row0 + wid * 64 + i * 16 + lq * 4 + reg;
            if (r < NROWS) {
                out[(size_t)r * KCL + lm]      = acc[i][0][reg] + kst[0];
                out[(size_t)r * KCL + 16 + lm] = acc[i][1][reg] + kst[1];
            }
        }
    }
}

// ---------------------------------------------------------------------------
extern "C" void kernel_launch(void* const* d_in, const int* in_sizes, int n_in,
                              void* d_out, int out_size, void* d_ws, size_t ws_size,
                              hipStream_t stream)
{
    const float* x  = (const float*)d_in[0];
    const float* W1 = (const float*)d_in[1];
    const float* b1 = (const float*)d_in[2];
    const float* W2 = (const float*)d_in[3];
    const float* b2 = (const float*)d_in[4];
    const float* W3 = (const float*)d_in[5];
    const float* b3 = (const float*)d_in[6];
    float* out = (float*)d_out;              // [N*K] gmm_log, then [K*D] vars

    float* ws = (float*)d_ws;
    float* h1      = ws;                         // 51,200,000 f
    float* h2      = h1 + (size_t)NROWS * H1DIM; // 25,600,000 f
    float* att     = h2 + (size_t)NROWS * H2DIM; //  3,200,000 f
    float* P       = att + (size_t)NROWS * KCL;  //  6,422,528 f
    float* Patt    = P + (size_t)16 * NCHUNK * 2048;
    float* S12     = Patt + NCHUNK * KCL;
    float* att_sum = S12 + 2 * KCL * DDIM;
    short* Bp      = (short*)(att_sum + KCL);    // [32][1024] bf16
    float* konst   = (float*)(Bp + KCL * 1024);
    (void)ws_size; (void)in_sizes; (void)n_in; (void)out_size;

    // Weight splits overlay the P region (dead until stats_partial writes P).
    short* W1hT = (short*)P;
    short* W1lT = W1hT + H1DIM * DDIM;
    short* W2hT = W1lT + H1DIM * DDIM;
    short* W2lT = W2hT + H2DIM * H1DIM;

    split_weightT<<<dim3((DDIM * H1DIM + 255) / 256), 256, 0, stream>>>(
        W1, DDIM, H1DIM, W1hT, W1lT);
    split_weightT<<<dim3((H1DIM * H2DIM + 255) / 256), 256, 0, stream>>>(
        W2, H1DIM, H2DIM, W2hT, W2lT);

    int mblocks = (NROWS + 127) / 128;   // 782

    gemm_split_softplus<<<dim3(H1DIM / 128, mblocks), 256, 0, stream>>>(
        x, W1hT, W1lT, b1, h1, NROWS, H1DIM, DDIM);
    gemm_split_softplus<<<dim3(H2DIM / 128, mblocks), 256, 0, stream>>>(
        h1, W2hT, W2lT, b2, h2, NROWS, H2DIM, H1DIM);
    logits_softmax<<<dim3((NROWS + 255) / 256), 256, 0, stream>>>(h2, W3, b3, att);
    stats_partial<<<dim3(NCHUNK, DDIM / 32), 256, 0, stream>>>(x, att, P, Patt);
    stats_reduce<<<dim3(128), 256, 0, stream>>>(P, Patt, S12, att_sum);
    finalize_stats<<<dim3(KCL), 256, 0, stream>>>(
        S12, att_sum, Bp, konst, out + (size_t)NROWS * KCL);
    gmm_out_mfma<<<dim3((NROWS + 255) / 256), 256, 0, stream>>>(x, Bp, konst, out);
}

// Round 4
// 1197.422 us; speedup vs baseline: 2.1161x; 1.0687x over previous
//
#include <hip/hip_runtime.h>
#include <hip/hip_bf16.h>
#include <math.h>

// Problem constants
#define NROWS 100000
#define DDIM  512
#define KCL   32
#define H1DIM 512
#define H2DIM 256
#define LN2PI_2 0.9189385332046727f
#define NCHUNK 196   // ceil(100000/512)

typedef __attribute__((ext_vector_type(8))) short short8;
typedef __attribute__((ext_vector_type(4))) short shortx4;
typedef __attribute__((ext_vector_type(4))) float floatx4;

__device__ __forceinline__ float softplus_f(float v) {
    return v > 20.f ? v : log1pf(expf(v));
}

__device__ __forceinline__ unsigned short f2bf_rne(float f) {
    unsigned int u = __float_as_uint(f);
    return (unsigned short)((u + 0x7fffu + ((u >> 16) & 1u)) >> 16);
}

// ---------------------------------------------------------------------------
// x (fp32) -> bf16, 8 elements/thread. Grid exactly N*D/2048 = 25000 blocks.
// ---------------------------------------------------------------------------
__global__ __launch_bounds__(256) void cvt_x_bf16(
    const float* __restrict__ x, short* __restrict__ xb)
{
    size_t i = ((size_t)blockIdx.x * 256 + threadIdx.x) * 8;
    float4 f0 = *(const float4*)&x[i];
    float4 f1 = *(const float4*)&x[i + 4];
    short8 o;
    o[0] = (short)f2bf_rne(f0.x); o[1] = (short)f2bf_rne(f0.y);
    o[2] = (short)f2bf_rne(f0.z); o[3] = (short)f2bf_rne(f0.w);
    o[4] = (short)f2bf_rne(f1.x); o[5] = (short)f2bf_rne(f1.y);
    o[6] = (short)f2bf_rne(f1.z); o[7] = (short)f2bf_rne(f1.w);
    *(short8*)&xb[i] = o;
}

// ---------------------------------------------------------------------------
// W[k][n] fp32 -> transposed bf16 BT[n][k].
// ---------------------------------------------------------------------------
__global__ __launch_bounds__(256) void cvt_weightT(
    const float* __restrict__ W, int Kd, int Nc, short* __restrict__ BT)
{
    int idx = blockIdx.x * 256 + threadIdx.x;
    if (idx >= Kd * Nc) return;
    int n = idx % Nc, k = idx / Nc;
    BT[(size_t)n * Kd + k] = (short)f2bf_rne(W[idx]);
}

// ---------------------------------------------------------------------------
// C = softplus(A @ B^T + bias). A bf16 [M][Kd], BT bf16 [Nc][Kd].
// Tile 128x128x64, 256 thr (4 waves), 4x4 frags of mfma_f32_16x16x32_bf16.
// Staging is pure short8 copies (no conversion in the K-loop).
// out_bf16: write C as bf16 (h1) or fp32 (h2).
// ---------------------------------------------------------------------------
#define LDT 72   // LDS row stride in shorts (144 B, 16B-aligned, padded)
__global__ __launch_bounds__(256) void gemm_bf16_softplus(
    const short* __restrict__ A, const short* __restrict__ BT,
    const float* __restrict__ bias, void* __restrict__ Cptr,
    int M, int Nc, int Kd, int out_bf16)
{
    __shared__ short As[128 * LDT];
    __shared__ short Bs[128 * LDT];

    const int tid = threadIdx.x;
    const int lane = tid & 63;
    const int lm = lane & 15;
    const int lq = lane >> 4;
    const int wid = tid >> 6;
    const int wrow = (wid & 1) * 64;
    const int wcol = (wid >> 1) * 64;

    const int row0 = blockIdx.y * 128;
    const int col0 = blockIdx.x * 128;

    floatx4 acc[4][4];
    #pragma unroll
    for (int i = 0; i < 4; i++)
        #pragma unroll
        for (int j = 0; j < 4; j++)
            acc[i][j] = (floatx4){0.f, 0.f, 0.f, 0.f};

    const int nk = Kd >> 6;
    for (int kt = 0; kt < nk; kt++) {
        __syncthreads();
        // stage A,B: 128 rows x 64 k each (8 KB bf16), 2 chunks/thread/matrix
        #pragma unroll
        for (int h = 0; h < 4; h++) {
            int u = tid + h * 256;      // 0..1023
            int r = u >> 3;             // 0..127
            int c = (u & 7) << 3;       // 0,8,..,56 (shorts)
            int gr = row0 + r; if (gr > M - 1) gr = M - 1;
            *(short8*)&As[r * LDT + c] =
                *(const short8*)&A[(size_t)gr * Kd + (kt << 6) + c];
            *(short8*)&Bs[r * LDT + c] =
                *(const short8*)&BT[(size_t)(col0 + r) * Kd + (kt << 6) + c];
        }
        __syncthreads();

        #pragma unroll
        for (int step = 0; step < 2; step++) {
            short8 a[4], b[4];
            #pragma unroll
            for (int i = 0; i < 4; i++)
                a[i] = *(const short8*)&As[(wrow + i * 16 + lm) * LDT + step * 32 + lq * 8];
            #pragma unroll
            for (int j = 0; j < 4; j++)
                b[j] = *(const short8*)&Bs[(wcol + j * 16 + lm) * LDT + step * 32 + lq * 8];
            #pragma unroll
            for (int i = 0; i < 4; i++)
                #pragma unroll
                for (int j = 0; j < 4; j++)
                    acc[i][j] = __builtin_amdgcn_mfma_f32_16x16x32_bf16(
                        a[i], b[j], acc[i][j], 0, 0, 0);
        }
    }

    float bb[4];
    #pragma unroll
    for (int j = 0; j < 4; j++)
        bb[j] = bias[col0 + wcol + j * 16 + lm];

    #pragma unroll
    for (int i = 0; i < 4; i++) {
        #pragma unroll
        for (int reg = 0; reg < 4; reg++) {
            int r = row0 + wrow + i * 16 + lq * 4 + reg;
            if (r < M) {
                #pragma unroll
                for (int j = 0; j < 4; j++) {
                    int c = col0 + wcol + j * 16 + lm;
                    float v = softplus_f(acc[i][j][reg] + bb[j]);
                    if (out_bf16)
                        ((short*)Cptr)[(size_t)r * Nc + c] = (short)f2bf_rne(v);
                    else
                        ((float*)Cptr)[(size_t)r * Nc + c] = v;
                }
            }
        }
    }
}

// ---------------------------------------------------------------------------
// logits = h2 @ W3 + b3, softmax over K=32 -> att [N,K]
// ---------------------------------------------------------------------------
__global__ __launch_bounds__(256) void logits_softmax(
    const float* __restrict__ h2, const float* __restrict__ W3,
    const float* __restrict__ b3, float* __restrict__ att)
{
    __shared__ float W3s[H2DIM][KCL];
    __shared__ float Hs[256][33];
    __shared__ float b3s[KCL];

    int tid = threadIdx.x;
    int n0 = blockIdx.x * 256;
    int n = n0 + tid;

    for (int idx = tid; idx < H2DIM * KCL; idx += 256)
        ((float*)W3s)[idx] = W3[idx];
    if (tid < KCL) b3s[tid] = b3[tid];

    float acc[KCL] = {};

    for (int t = 0; t < H2DIM / 32; t++) {
        __syncthreads();
        for (int idx = tid; idx < 256 * 32; idx += 256) {
            int r = idx >> 5, c = idx & 31;
            int g = n0 + r;
            Hs[r][c] = (g < NROWS) ? h2[(size_t)g * H2DIM + t * 32 + c] : 0.f;
        }
        __syncthreads();
        #pragma unroll 8
        for (int j = 0; j < 32; j++) {
            float hv = Hs[tid][j];
            #pragma unroll
            for (int k4 = 0; k4 < KCL / 4; k4++) {
                float4 w = *(const float4*)&W3s[t * 32 + j][k4 * 4];
                acc[k4 * 4 + 0] += hv * w.x;
                acc[k4 * 4 + 1] += hv * w.y;
                acc[k4 * 4 + 2] += hv * w.z;
                acc[k4 * 4 + 3] += hv * w.w;
            }
        }
    }

    if (n < NROWS) {
        float m = -INFINITY;
        #pragma unroll
        for (int k = 0; k < KCL; k++) { acc[k] += b3s[k]; m = fmaxf(m, acc[k]); }
        float s = 0.f;
        #pragma unroll
        for (int k = 0; k < KCL; k++) { acc[k] = expf(acc[k] - m); s += acc[k]; }
        float inv = 1.f / s;
        #pragma unroll
        for (int k4 = 0; k4 < KCL / 4; k4++) {
            float4 o;
            o.x = acc[k4 * 4 + 0] * inv;
            o.y = acc[k4 * 4 + 1] * inv;
            o.z = acc[k4 * 4 + 2] * inv;
            o.w = acc[k4 * 4 + 3] * inv;
            *(float4*)&att[(size_t)n * KCL + k4 * 4] = o;
        }
    }
}

// ---------------------------------------------------------------------------
// Partial weighted moments (no atomics; reduced by stats_reduce).
// ---------------------------------------------------------------------------
__global__ __launch_bounds__(256) void stats_partial(
    const float* __restrict__ x, const float* __restrict__ att,
    float* __restrict__ P, float* __restrict__ Patt)
{
    __shared__ float as_[128][32];
    __shared__ float xs[128][32];

    int tid = threadIdx.x;
    int c = blockIdx.x;
    int t = blockIdx.y;
    int k = tid & 31;
    int dg = tid >> 5;

    float s1[4] = {}, s2[4] = {};
    float asum = 0.f;
    int r0 = c * 512;

    for (int sub = 0; sub < 4; sub++) {
        int rr0 = r0 + sub * 128;
        __syncthreads();
        for (int idx = tid; idx < 128 * 32; idx += 256) {
            int r = idx >> 5, cc = idx & 31;
            int g = rr0 + r;
            as_[r][cc] = (g < NROWS) ? att[(size_t)g * KCL + cc] : 0.f;
            xs[r][cc]  = (g < NROWS) ? x[(size_t)g * DDIM + t * 32 + cc] : 0.f;
        }
        __syncthreads();
        for (int r = 0; r < 128; r++) {
            float a = as_[r][k];
            if (dg == 0) asum += a;
            float4 xv = *(const float4*)&xs[r][dg * 4];
            float ax;
            ax = a * xv.x; s1[0] += ax; s2[0] += ax * xv.x;
            ax = a * xv.y; s1[1] += ax; s2[1] += ax * xv.y;
            ax = a * xv.z; s1[2] += ax; s2[2] += ax * xv.z;
            ax = a * xv.w; s1[3] += ax; s2[3] += ax * xv.w;
        }
    }

    size_t base = ((size_t)(t * NCHUNK + c)) * 2048;
    #pragma unroll
    for (int i = 0; i < 4; i++) {
        P[base + k * 32 + dg * 4 + i]        = s1[i];
        P[base + 1024 + k * 32 + dg * 4 + i] = s2[i];
    }
    if (t == 0 && dg == 0) Patt[c * 32 + k] = asum;
}

// ---------------------------------------------------------------------------
// Reduce partials: 128 blocks (16 d-tiles x 8 e-slices), 1 element/thread.
// ---------------------------------------------------------------------------
__global__ __launch_bounds__(256) void stats_reduce(
    const float* __restrict__ P, const float* __restrict__ Patt,
    float* __restrict__ S12, float* __restrict__ att_sum)
{
    int t = blockIdx.x >> 3;
    int s = blockIdx.x & 7;
    int e = s * 256 + threadIdx.x;
    float sum = 0.f;
    for (int c = 0; c < NCHUNK; c++)
        sum += P[((size_t)(t * NCHUNK + c)) * 2048 + e];
    int which = e >> 10;
    int ee = e & 1023;
    int k = ee >> 5, dd = ee & 31;
    S12[(size_t)which * KCL * DDIM + k * DDIM + t * 32 + dd] = sum;

    if (blockIdx.x == 0 && threadIdx.x < KCL) {
        float as = 0.f;
        for (int c = 0; c < NCHUNK; c++) as += Patt[c * 32 + threadIdx.x];
        att_sum[threadIdx.x] = as;
    }
}

// ---------------------------------------------------------------------------
// Finalize stats: vars (to out), bf16 B' = [-0.5/v | m/v] per class, konst.
// ---------------------------------------------------------------------------
__global__ __launch_bounds__(256) void finalize_stats(
    const float* __restrict__ S12, const float* __restrict__ att_sum,
    short* __restrict__ Bp, float* __restrict__ konst,
    float* __restrict__ vars_out)
{
    int k = blockIdx.x;
    int tid = threadIdx.x;
    __shared__ float red[256];

    float inv_as = 1.f / att_sum[k];
    float csum = 0.f, lsum = 0.f;
    for (int d = tid; d < DDIM; d += 256) {
        float mean = S12[k * DDIM + d] * inv_as;
        float ex2  = S12[KCL * DDIM + k * DDIM + d] * inv_as;
        float var  = ex2 - mean * mean;
        vars_out[k * DDIM + d] = var;
        float iv = 1.f / var;
        Bp[(size_t)k * 1024 + d]       = (short)f2bf_rne(-0.5f * iv);
        Bp[(size_t)k * 1024 + 512 + d] = (short)f2bf_rne(mean * iv);
        csum += mean * mean * iv;
        lsum += logf(var);
    }
    red[tid] = csum;
    __syncthreads();
    for (int s = 128; s > 0; s >>= 1) {
        if (tid < s) red[tid] += red[tid + s];
        __syncthreads();
    }
    float ctot = red[0];
    __syncthreads();
    red[tid] = lsum;
    __syncthreads();
    for (int s = 128; s > 0; s >>= 1) {
        if (tid < s) red[tid] += red[tid + s];
        __syncthreads();
    }
    if (tid == 0)
        konst[k] = -0.5f * ctot - 0.5f * red[0] - DDIM * LN2PI_2;
}

// ---------------------------------------------------------------------------
// gmm_log via MFMA: out[n,k] = [x^2|x] @ Bp[k]^T + konst[k].
// ---------------------------------------------------------------------------
#define LDG 40
__global__ __launch_bounds__(256) void gmm_out_mfma(
    const float* __restrict__ x, const short* __restrict__ Bp,
    const float* __restrict__ konst, float* __restrict__ out)
{
    __shared__ short As_sq[256 * LDG];
    __shared__ short As_x[256 * LDG];

    const int tid = threadIdx.x;
    const int lane = tid & 63;
    const int lm = lane & 15;
    const int lq = lane >> 4;
    const int wid = tid >> 6;
    const int row0 = blockIdx.x * 256;

    floatx4 acc[4][2];
    #pragma unroll
    for (int i = 0; i < 4; i++)
        #pragma unroll
        for (int j = 0; j < 2; j++)
            acc[i][j] = (floatx4){0.f, 0.f, 0.f, 0.f};

    for (int dt = 0; dt < 16; dt++) {
        __syncthreads();
        #pragma unroll
        for (int h = 0; h < 8; h++) {
            int u = tid + h * 256;
            int r = u >> 3;
            int seg = (u & 7) << 2;
            int gr = row0 + r;
            float4 v = make_float4(0.f, 0.f, 0.f, 0.f);
            if (gr < NROWS)
                v = *(const float4*)&x[(size_t)gr * DDIM + dt * 32 + seg];
            shortx4 sx, sq;
            sx[0] = (short)f2bf_rne(v.x); sq[0] = (short)f2bf_rne(v.x * v.x);
            sx[1] = (short)f2bf_rne(v.y); sq[1] = (short)f2bf_rne(v.y * v.y);
            sx[2] = (short)f2bf_rne(v.z); sq[2] = (short)f2bf_rne(v.z * v.z);
            sx[3] = (short)f2bf_rne(v.w); sq[3] = (short)f2bf_rne(v.w * v.w);
            *(shortx4*)&As_x[r * LDG + seg]  = sx;
            *(shortx4*)&As_sq[r * LDG + seg] = sq;
        }
        __syncthreads();

        short8 a_sq[4], a_x[4], b_sq[2], b_x[2];
        #pragma unroll
        for (int i = 0; i < 4; i++) {
            int off = (wid * 64 + i * 16 + lm) * LDG + lq * 8;
            a_sq[i] = *(const short8*)&As_sq[off];
            a_x[i]  = *(const short8*)&As_x[off];
        }
        #pragma unroll
        for (int j = 0; j < 2; j++) {
            const size_t bo = (size_t)(j * 16 + lm) * 1024 + dt * 32 + lq * 8;
            b_sq[j] = *(const short8*)&Bp[bo];
            b_x[j]  = *(const short8*)&Bp[bo + 512];
        }
        #pragma unroll
        for (int i = 0; i < 4; i++)
            #pragma unroll
            for (int j = 0; j < 2; j++) {
                acc[i][j] = __builtin_amdgcn_mfma_f32_16x16x32_bf16(
                    a_sq[i], b_sq[j], acc[i][j], 0, 0, 0);
                acc[i][j] = __builtin_amdgcn_mfma_f32_16x16x32_bf16(
                    a_x[i], b_x[j], acc[i][j], 0, 0, 0);
            }
    }

    float kst[2];
    kst[0] = konst[lm];
    kst[1] = konst[16 + lm];

    #pragma unroll
    for (int i = 0; i < 4; i++) {
        #pragma unroll
        for (int reg = 0; reg < 4; reg++) {
            int r = row0 + wid * 64 + i * 16 + lq * 4 + reg;
            if (r < NROWS) {
                out[(size_t)r * KCL + lm]      = acc[i][0][reg] + kst[0];
                out[(size_t)r * KCL + 16 + lm] = acc[i][1][reg] + kst[1];
            }
        }
    }
}

// ---------------------------------------------------------------------------
extern "C" void kernel_launch(void* const* d_in, const int* in_sizes, int n_in,
                              void* d_out, int out_size, void* d_ws, size_t ws_size,
                              hipStream_t stream)
{
    const float* x  = (const float*)d_in[0];
    const float* W1 = (const float*)d_in[1];
    const float* b1 = (const float*)d_in[2];
    const float* W2 = (const float*)d_in[3];
    const float* b2 = (const float*)d_in[4];
    const float* W3 = (const float*)d_in[5];
    const float* b3 = (const float*)d_in[6];
    float* out = (float*)d_out;              // [N*K] gmm_log, then [K*D] vars

    // ws layout (total ~244 MB):
    short* h1b     = (short*)d_ws;                       // [N][512] bf16
    float* h2      = (float*)(h1b + (size_t)NROWS * H1DIM); // [N][256] fp32
    float* att     = h2 + (size_t)NROWS * H2DIM;
    float* P       = att + (size_t)NROWS * KCL;
    float* Patt    = P + (size_t)16 * NCHUNK * 2048;
    float* S12     = Patt + NCHUNK * KCL;
    float* att_sum = S12 + 2 * KCL * DDIM;
    short* Bp      = (short*)(att_sum + KCL);            // [32][1024] bf16
    float* konst   = (float*)(Bp + KCL * 1024);
    (void)ws_size; (void)in_sizes; (void)n_in; (void)out_size;

    // Overlays (stream-ordered, graph-safe):
    // xb lives in the h2 region: consumed by GEMM1 before GEMM2 writes h2.
    short* xb  = (short*)h2;                 // [N][512] bf16
    // Weight bf16 transposes live at the head of P (dead until stats_partial).
    short* W1T = (short*)P;                  // [512][512]
    short* W2T = W1T + H1DIM * DDIM;         // [256][512]

    cvt_x_bf16<<<dim3(NROWS * DDIM / 2048), 256, 0, stream>>>(x, xb);
    cvt_weightT<<<dim3((DDIM * H1DIM + 255) / 256), 256, 0, stream>>>(
        W1, DDIM, H1DIM, W1T);
    cvt_weightT<<<dim3((H1DIM * H2DIM + 255) / 256), 256, 0, stream>>>(
        W2, H1DIM, H2DIM, W2T);

    int mblocks = (NROWS + 127) / 128;   // 782

    // h1 = softplus(x @ W1 + b1), bf16 out
    gemm_bf16_softplus<<<dim3(H1DIM / 128, mblocks), 256, 0, stream>>>(
        xb, W1T, b1, (void*)h1b, NROWS, H1DIM, DDIM, 1);
    // h2 = softplus(h1 @ W2 + b2), fp32 out
    gemm_bf16_softplus<<<dim3(H2DIM / 128, mblocks), 256, 0, stream>>>(
        h1b, W2T, b2, (void*)h2, NROWS, H2DIM, H1DIM, 0);
    logits_softmax<<<dim3((NROWS + 255) / 256), 256, 0, stream>>>(h2, W3, b3, att);
    stats_partial<<<dim3(NCHUNK, DDIM / 32), 256, 0, stream>>>(x, att, P, Patt);
    stats_reduce<<<dim3(128), 256, 0, stream>>>(P, Patt, S12, att_sum);
    finalize_stats<<<dim3(KCL), 256, 0, stream>>>(
        S12, att_sum, Bp, konst, out + (size_t)NROWS * KCL);
    gmm_out_mfma<<<dim3((NROWS + 255) / 256), 256, 0, stream>>>(x, Bp, konst, out);
}